// Round 1
// baseline (572.172 us; speedup 1.0000x reference)
//
#include <hip/hip_runtime.h>
#include <hip/hip_bf16.h>

#define TT 2048
#define HD 2048
#define ID 2048
#define NE 8

typedef __attribute__((ext_vector_type(8))) short short8;
typedef __attribute__((ext_vector_type(4))) float f4;

__device__ __forceinline__ int slz(int r){ return ((r ^ (r >> 3)) & 7); }

__device__ __forceinline__ unsigned short b16(float f){
  union { __hip_bfloat16 b; unsigned short u; } x;
  x.b = __float2bfloat16(f);
  return x.u;
}
__device__ __forceinline__ unsigned pk2(float lo, float hi){
  return (unsigned)b16(lo) | ((unsigned)b16(hi) << 16);
}
__device__ __forceinline__ float gelu_t(float x){
  float y = 0.7978845608028654f * (x + 0.044715f * x * x * x);
  float t = 1.0f - 2.0f / (__expf(2.0f * y) + 1.0f);
  return 0.5f * x * (1.0f + t);
}

// ---------------- routing: softmax over 8, top-2, renorm, scale ----------------
__global__ void k_route(const float* __restrict__ lg, const float* __restrict__ sc,
                        int* __restrict__ rid, float* __restrict__ rw){
  int t = blockIdx.x * blockDim.x + threadIdx.x;
  if (t >= TT) return;
  float l[NE];
#pragma unroll
  for (int e = 0; e < NE; e++) l[e] = lg[t * NE + e];
  float mx = l[0];
#pragma unroll
  for (int e = 1; e < NE; e++) mx = fmaxf(mx, l[e]);
  float p[NE];
#pragma unroll
  for (int e = 0; e < NE; e++) p[e] = __expf(l[e] - mx);
  int i0 = 0; float b0 = l[0];
#pragma unroll
  for (int e = 1; e < NE; e++) if (l[e] > b0){ b0 = l[e]; i0 = e; }
  int i1 = -1; float b1 = -1e30f;
#pragma unroll
  for (int e = 0; e < NE; e++) if (e != i0 && l[e] > b1){ b1 = l[e]; i1 = e; }
  float p0 = p[i0], p1 = p[i1];
  float rn = p0 + p1; rn = (rn > 0.f) ? rn : 1.f;   // softmax denom cancels in renorm
  rw[t*2]   = p0 / rn * sc[i0];
  rw[t*2+1] = p1 / rn * sc[i1];
  rid[t*2]  = i0;
  rid[t*2+1]= i1;
}

// ------------- deterministic per-expert compaction (1 wave, ballot prefix) -------------
__global__ void k_lists(const int* __restrict__ rid, const float* __restrict__ rw,
                        int* __restrict__ row_tok, float* __restrict__ row_w,
                        int* __restrict__ off){
  int lane = threadIdx.x;            // 64 threads
  int ids[64]; float wv[64];
#pragma unroll
  for (int i = 0; i < 64; i++) ids[i] = rid[i * 64 + lane];
#pragma unroll
  for (int i = 0; i < 64; i++) wv[i] = rw[i * 64 + lane];

  int cnt[NE];
#pragma unroll
  for (int e = 0; e < NE; e++) cnt[e] = 0;
#pragma unroll
  for (int i = 0; i < 64; i++){
#pragma unroll
    for (int e = 0; e < NE; e++)
      cnt[e] += __popcll(__ballot(ids[i] == e));
  }
  int offs[NE + 1]; offs[0] = 0;
#pragma unroll
  for (int e = 0; e < NE; e++) offs[e + 1] = offs[e] + cnt[e];
  if (lane == 0){
#pragma unroll
    for (int e = 0; e <= NE; e++) off[e] = offs[e];
  }
  int run[NE];
#pragma unroll
  for (int e = 0; e < NE; e++) run[e] = offs[e];
  unsigned long long ltm = (1ULL << lane) - 1ULL;
#pragma unroll
  for (int i = 0; i < 64; i++){
    int id = ids[i];
    int tok = (i * 64 + lane) >> 1;
#pragma unroll
    for (int e = 0; e < NE; e++){
      unsigned long long m = __ballot(id == e);
      if (id == e){
        int pos = run[e] + __popcll(m & ltm);
        row_tok[pos] = tok;
        row_w[pos]   = wv[i];
      }
      run[e] += __popcll(m);
    }
  }
}

// ---------------- gate+up grouped GEMM: 128x128 dual-output tile, BK=64 ----------------
__global__ __launch_bounds__(256, 2)
void k_gateup(const float* __restrict__ X, const float* __restrict__ Wg,
              const float* __restrict__ Wu, const int* __restrict__ row_tok,
              const int* __restrict__ off, __hip_bfloat16* __restrict__ hbuf){
  __shared__ __align__(16) char sA[16384];   // [128 m][64 k] bf16, XOR-swizzled rows
  __shared__ __align__(16) char sBg[16384];  // [128 n][64 k] bf16
  __shared__ __align__(16) char sBu[16384];
  __shared__ int s_tok[128];

  const int bid = blockIdx.x;
  const int e  = bid & 7;            // XCD pin: dispatch round-robin -> expert == XCD
  const int mt = (bid >> 3) & 15;    // m-tile innermost within XCD for B-panel L2 reuse
  const int nt = bid >> 7;           // 0..15
  const int o0 = off[e], o1 = off[e + 1];
  const int cnt = o1 - o0;
  if (mt * 128 >= cnt) return;
  const int p0 = o0 + mt * 128;
  const int cntL = min(128, cnt - mt * 128);
  const int tid = threadIdx.x;

  if (tid < 128){
    int p = p0 + tid; if (p > TT*2 - 1) p = TT*2 - 1;
    s_tok[tid] = row_tok[p];
  }
  __syncthreads();

  // A staging: thread covers k-quad (tid&15), rows tm+16s
  const int tq = tid & 15, tm = tid >> 4;
  const float* aptr[8]; int awoff[8];
#pragma unroll
  for (int s = 0; s < 8; s++){
    int m = tm + s * 16;
    aptr[s] = X + (size_t)s_tok[m] * HD + tq * 4;
    awoff[s] = m * 128 + ((tq * 8) ^ (slz(m) << 4));
  }
  // B staging: float4 over n, 4 k-rows, register 4x4 transpose
  const int bn0 = (tid & 31) * 4;
  const int bk0 = (tid >> 5) * 4;
  const size_t wbase = (size_t)e * HD * ID + (size_t)bk0 * ID + (size_t)nt * 128 + bn0;
  const float* gptr = Wg + wbase;
  const float* uptr = Wu + wbase;
  int bwoff[2][4];
#pragma unroll
  for (int pp = 0; pp < 2; pp++)
#pragma unroll
    for (int j = 0; j < 4; j++){
      int n = bn0 + j;
      bwoff[pp][j] = n * 128 + (((bk0 + pp * 32) * 2) ^ (slz(n) << 4));
    }

  const int wid = tid >> 6, lane = tid & 63;
  const int wm = wid >> 1, wn = wid & 1;   // 2x2 waves, each 64x64 (dual)
  f4 accg[4][4], accu[4][4];
#pragma unroll
  for (int a = 0; a < 4; a++)
#pragma unroll
    for (int b = 0; b < 4; b++){ accg[a][b] = f4{0,0,0,0}; accu[a][b] = f4{0,0,0,0}; }

  for (int kt = 0; kt < HD / 64; ++kt){
    __syncthreads();
    // ---- stage A (gathered token rows, fp32 -> bf16) ----
#pragma unroll
    for (int s = 0; s < 8; s++){
      f4 v = *(const f4*)(aptr[s] + kt * 64);
      *(uint2*)(sA + awoff[s]) = uint2{ pk2(v[0], v[1]), pk2(v[2], v[3]) };
    }
    // ---- stage Bg/Bu (fp32 -> bf16, 4x4 transpose to [n][k]) ----
#pragma unroll
    for (int pp = 0; pp < 2; pp++){
      const float* gk = gptr + (size_t)(kt * 64 + pp * 32) * ID;
      f4 g0 = *(const f4*)(gk);
      f4 g1 = *(const f4*)(gk + ID);
      f4 g2 = *(const f4*)(gk + 2 * ID);
      f4 g3 = *(const f4*)(gk + 3 * ID);
#pragma unroll
      for (int j = 0; j < 4; j++)
        *(uint2*)(sBg + bwoff[pp][j]) = uint2{ pk2(g0[j], g1[j]), pk2(g2[j], g3[j]) };
      const float* uk = uptr + (size_t)(kt * 64 + pp * 32) * ID;
      f4 u0 = *(const f4*)(uk);
      f4 u1 = *(const f4*)(uk + ID);
      f4 u2 = *(const f4*)(uk + 2 * ID);
      f4 u3 = *(const f4*)(uk + 3 * ID);
#pragma unroll
      for (int j = 0; j < 4; j++)
        *(uint2*)(sBu + bwoff[pp][j]) = uint2{ pk2(u0[j], u1[j]), pk2(u2[j], u3[j]) };
    }
    __syncthreads();
    // ---- compute ----
#pragma unroll
    for (int ks = 0; ks < 2; ++ks){
      short8 af[4], bgf[4], buf_[4];
      const int kb = ks * 64 + (lane >> 4) * 16;
#pragma unroll
      for (int f = 0; f < 4; f++){
        int m = wm * 64 + f * 16 + (lane & 15);
        af[f] = *(const short8*)(sA + m * 128 + (kb ^ (slz(m) << 4)));
        int n = wn * 64 + f * 16 + (lane & 15);
        bgf[f] = *(const short8*)(sBg + n * 128 + (kb ^ (slz(n) << 4)));
        buf_[f] = *(const short8*)(sBu + n * 128 + (kb ^ (slz(n) << 4)));
      }
#pragma unroll
      for (int fm = 0; fm < 4; fm++)
#pragma unroll
        for (int fn = 0; fn < 4; fn++){
          accg[fm][fn] = __builtin_amdgcn_mfma_f32_16x16x32_bf16(af[fm], bgf[fn], accg[fm][fn], 0, 0, 0);
          accu[fm][fn] = __builtin_amdgcn_mfma_f32_16x16x32_bf16(af[fm], buf_[fn], accu[fm][fn], 0, 0, 0);
        }
    }
  }
  // ---- epilogue: h = gelu(g)*u -> bf16 ----
#pragma unroll
  for (int fm = 0; fm < 4; fm++){
#pragma unroll
    for (int r = 0; r < 4; r++){
      int row = wm * 64 + fm * 16 + (lane >> 4) * 4 + r;
      if (row < cntL){
        size_t base = (size_t)(p0 + row) * ID + (size_t)nt * 128 + wn * 64 + (lane & 15);
#pragma unroll
        for (int fn = 0; fn < 4; fn++){
          float g = accg[fm][fn][r];
          float u = accu[fm][fn][r];
          hbuf[base + fn * 16] = __float2bfloat16(gelu_t(g) * u);
        }
      }
    }
  }
}

// ---------------- down GEMM + weighted atomic scatter ----------------
__global__ __launch_bounds__(256, 2)
void k_down(const __hip_bfloat16* __restrict__ hbuf, const float* __restrict__ Wd,
            const int* __restrict__ row_tok, const float* __restrict__ row_w,
            const int* __restrict__ off, float* __restrict__ out){
  __shared__ __align__(16) char sA[16384];   // [128 m][64 k] bf16 swizzled
  __shared__ __align__(16) char sB[16384];   // [128 n][64 k] bf16 swizzled
  __shared__ int s_tok[128];
  __shared__ float s_w[128];

  const int bid = blockIdx.x;
  const int e  = bid & 7;
  const int mt = (bid >> 3) & 15;
  const int nt = bid >> 7;
  const int o0 = off[e], o1 = off[e + 1];
  const int cnt = o1 - o0;
  if (mt * 128 >= cnt) return;
  const int p0 = o0 + mt * 128;
  const int cntL = min(128, cnt - mt * 128);
  const int tid = threadIdx.x;

  if (tid < 128){
    int p = p0 + tid; if (p > TT*2 - 1) p = TT*2 - 1;
    s_tok[tid] = row_tok[p];
    s_w[tid]   = row_w[p];
  }
  __syncthreads();

  // A staging: bf16 rows copied 16B-chunkwise with dest swizzle
  const char* asrc[4]; int awoff[4];
#pragma unroll
  for (int s = 0; s < 4; s++){
    int c = s * 256 + tid;            // 1024 chunks of 16B
    int m = c >> 3, cb = (c & 7) * 16;
    int p = p0 + m; if (p > TT*2 - 1) p = TT*2 - 1;
    asrc[s] = (const char*)hbuf + (size_t)p * (ID * 2) + cb;
    awoff[s] = m * 128 + (cb ^ (slz(m) << 4));
  }
  const int bn0 = (tid & 31) * 4;
  const int bk0 = (tid >> 5) * 4;
  const float* bptr = Wd + (size_t)e * ID * HD + (size_t)bk0 * HD + (size_t)nt * 128 + bn0;
  int bwoff[2][4];
#pragma unroll
  for (int pp = 0; pp < 2; pp++)
#pragma unroll
    for (int j = 0; j < 4; j++){
      int n = bn0 + j;
      bwoff[pp][j] = n * 128 + (((bk0 + pp * 32) * 2) ^ (slz(n) << 4));
    }

  const int wid = tid >> 6, lane = tid & 63;
  const int wm = wid >> 1, wn = wid & 1;
  f4 acc[4][4];
#pragma unroll
  for (int a = 0; a < 4; a++)
#pragma unroll
    for (int b = 0; b < 4; b++) acc[a][b] = f4{0,0,0,0};

  for (int kt = 0; kt < ID / 64; ++kt){
    __syncthreads();
#pragma unroll
    for (int s = 0; s < 4; s++){
      uint4 v = *(const uint4*)(asrc[s] + kt * 128);
      *(uint4*)(sA + awoff[s]) = v;
    }
#pragma unroll
    for (int pp = 0; pp < 2; pp++){
      const float* bk = bptr + (size_t)(kt * 64 + pp * 32) * HD;
      f4 b0 = *(const f4*)(bk);
      f4 b1 = *(const f4*)(bk + HD);
      f4 b2 = *(const f4*)(bk + 2 * HD);
      f4 b3 = *(const f4*)(bk + 3 * HD);
#pragma unroll
      for (int j = 0; j < 4; j++)
        *(uint2*)(sB + bwoff[pp][j]) = uint2{ pk2(b0[j], b1[j]), pk2(b2[j], b3[j]) };
    }
    __syncthreads();
#pragma unroll
    for (int ks = 0; ks < 2; ++ks){
      short8 af[4], bf[4];
      const int kb = ks * 64 + (lane >> 4) * 16;
#pragma unroll
      for (int f = 0; f < 4; f++){
        int m = wm * 64 + f * 16 + (lane & 15);
        af[f] = *(const short8*)(sA + m * 128 + (kb ^ (slz(m) << 4)));
        int n = wn * 64 + f * 16 + (lane & 15);
        bf[f] = *(const short8*)(sB + n * 128 + (kb ^ (slz(n) << 4)));
      }
#pragma unroll
      for (int fm = 0; fm < 4; fm++)
#pragma unroll
        for (int fn = 0; fn < 4; fn++)
          acc[fm][fn] = __builtin_amdgcn_mfma_f32_16x16x32_bf16(af[fm], bf[fn], acc[fm][fn], 0, 0, 0);
    }
  }
  // epilogue: out[tok] += w * y   (exactly 2 commutative fp32 adds per element)
#pragma unroll
  for (int fm = 0; fm < 4; fm++){
#pragma unroll
    for (int r = 0; r < 4; r++){
      int row = wm * 64 + fm * 16 + (lane >> 4) * 4 + r;
      if (row < cntL){
        int tok = s_tok[row];
        float w = s_w[row];
        float* ob = out + (size_t)tok * HD + (size_t)nt * 128 + wn * 64 + (lane & 15);
#pragma unroll
        for (int fn = 0; fn < 4; fn++)
          atomicAdd(ob + fn * 16, acc[fm][fn][r] * w);
      }
    }
  }
}

extern "C" void kernel_launch(void* const* d_in, const int* in_sizes, int n_in,
                              void* d_out, int out_size, void* d_ws, size_t ws_size,
                              hipStream_t stream){
  (void)in_sizes; (void)n_in; (void)out_size; (void)ws_size;
  const float* X  = (const float*)d_in[0];
  const float* RL = (const float*)d_in[1];
  const float* SC = (const float*)d_in[2];
  const float* Wg = (const float*)d_in[3];
  const float* Wu = (const float*)d_in[4];
  const float* Wd = (const float*)d_in[5];
  float* out = (float*)d_out;

  char* ws = (char*)d_ws;
  int*   rid     = (int*)(ws);
  float* rw      = (float*)(ws + 16384);
  int*   row_tok = (int*)(ws + 32768);
  float* row_w   = (float*)(ws + 49152);
  int*   off     = (int*)(ws + 65536);
  __hip_bfloat16* hbuf = (__hip_bfloat16*)(ws + 66560);   // 4096 x 2048 bf16 = 16 MiB

  hipMemsetAsync(d_out, 0, (size_t)TT * HD * sizeof(float), stream);
  k_route<<<TT / 256, 256, 0, stream>>>(RL, SC, rid, rw);
  k_lists<<<1, 64, 0, stream>>>(rid, rw, row_tok, row_w, off);
  k_gateup<<<2048, 256, 0, stream>>>(X, Wg, Wu, row_tok, off, hbuf);
  k_down<<<2048, 256, 0, stream>>>(hbuf, Wd, row_tok, row_w, off, out);
}